// Round 10
// baseline (71.343 us; speedup 1.0000x reference)
//
#include <hip/hip_runtime.h>
#include <hip/hip_bf16.h>
#include <cmath>

typedef __attribute__((ext_vector_type(8))) short short8;
typedef __attribute__((ext_vector_type(4))) float f32x4;

#define EPS_F 1e-7f
#define NEG_DIAG_F -10.0f
#define NPART 128           // per-row max slots: 64 direct (bx) + 64 transposed (by)

__device__ __forceinline__ void gload_lds16(const void* gptr, void* ldsptr) {
    __builtin_amdgcn_global_load_lds(
        (const __attribute__((address_space(1))) unsigned int*)gptr,
        (__attribute__((address_space(3))) unsigned int*)ldsptr,
        16, 0, 0);
}

// ---------------------------------------------------------------------------
// Kernel 1: row L2-normalize feat_k / feat_g (f32), cast to bf16; zero P.
// ---------------------------------------------------------------------------
__global__ void norm_cast_kernel(const float* __restrict__ fk, const float* __restrict__ fg,
                                 __hip_bfloat16* __restrict__ fkb, __hip_bfloat16* __restrict__ fgb,
                                 float* __restrict__ P, int N, int D) {
    int n = blockIdx.x;
    int t = threadIdx.x;
    float xk = fk[(size_t)n * D + t];
    float xg = fg[(size_t)n * D + t];
    float sk = xk * xk, sg = xg * xg;
#pragma unroll
    for (int off = 32; off > 0; off >>= 1) {
        sk += __shfl_xor(sk, off, 64);
        sg += __shfl_xor(sg, off, 64);
    }
    __shared__ float lsk[4], lsg[4];
    int w = t >> 6, l = t & 63;
    if (l == 0) { lsk[w] = sk; lsg[w] = sg; }
    __syncthreads();
    sk = lsk[0] + lsk[1] + lsk[2] + lsk[3];
    sg = lsg[0] + lsg[1] + lsg[2] + lsg[3];
    float rkv = 1.0f / (sqrtf(sk) + EPS_F);
    float rgv = 1.0f / (sqrtf(sg) + EPS_F);
    fkb[(size_t)n * D + t] = __float2bfloat16(xk * rkv);
    fgb[(size_t)n * D + t] = __float2bfloat16(xg * rgv);
    if (t < NPART) P[(size_t)n * NPART + t] = 0.0f;
}

// ---------------------------------------------------------------------------
// Kernel 2: 64x64-tile upper-triangle dual Gram, 4 waves (2x2), BK=32,
// DOUBLE-BUFFERED with counted vmcnt(4) + raw s_barrier (T3-minimum):
// next-tile stage issues before compute; no vmcnt(0) drain in the loop.
// Writes tile + transposed tile (bounce-coalesced) and per-tile row/col
// maxes to unique P slots.
// ---------------------------------------------------------------------------
__global__ __launch_bounds__(256, 4) void gram64_kernel(
    const __hip_bfloat16* __restrict__ fkb, const __hip_bfloat16* __restrict__ fgb,
    float* __restrict__ out, float* __restrict__ P, int N, int D) {

    __shared__ __align__(16) char smem[33280];   // 2x16K staging ∪ bounce[64][66]f32; lmax @32768
    float* bnc = (float*)smem;
    int* lmax = (int*)(smem + 32768);            // [0..63] row, [64..127] col

    int bx = blockIdx.x, by = blockIdx.y;
    if (bx < by) return;                         // lower triangle: skip
    int r0 = by * 64, c0 = bx * 64;

    int t = threadIdx.x;
    int w = t >> 6, l = t & 63;
    int wr = w >> 1, wc = w & 1;    // 2x2 wave grid; wave tile = 32 rows x 32 cols
    int lr = l & 15, lg = l >> 4;

    if (t < NPART) lmax[t] = 0;     // positive floats compare as ints

    // LDS read offsets: granule ^= (row>>1)&3
    int aoff[2], boff[2];
#pragma unroll
    for (int m = 0; m < 2; ++m) {
        int row = wr * 32 + m * 16 + lr;
        aoff[m] = row * 64 + ((lg ^ ((row >> 1) & 3)) << 4);
    }
#pragma unroll
    for (int n = 0; n < 2; ++n) {
        int row = wc * 32 + n * 16 + lr;
        boff[n] = row * 64 + ((lg ^ ((row >> 1) & 3)) << 4);
    }

    // staging addresses: thread t -> row t>>2, granule t&3, inverse-swizzled src
    int srow = t >> 2;
    int scsw = ((t & 3) ^ ((srow >> 1) & 3)) << 4;
    const char* pAk = (const char*)fkb + (size_t)(r0 + srow) * 512 + scsw;
    const char* pAg = (const char*)fgb + (size_t)(r0 + srow) * 512 + scsw;
    const char* pBk = (const char*)fkb + (size_t)(c0 + srow) * 512 + scsw;
    const char* pBg = (const char*)fgb + (size_t)(c0 + srow) * 512 + scsw;
    int sdst = w << 10;             // wave-uniform dest base (HW adds lane*16)

    f32x4 acck[2][2], accg[2][2];
    f32x4 zero = {0.f, 0.f, 0.f, 0.f};
#pragma unroll
    for (int m = 0; m < 2; ++m)
#pragma unroll
        for (int n = 0; n < 2; ++n) { acck[m][n] = zero; accg[m][n] = zero; }

    // prologue: stage k-step 0 into buf0
    gload_lds16(pAk, smem + sdst);
    gload_lds16(pAg, smem + 4096 + sdst);
    gload_lds16(pBk, smem + 8192 + sdst);
    gload_lds16(pBg, smem + 12288 + sdst);

    for (int ks = 0; ks < 8; ++ks) {
        char* cur = smem + (ks & 1) * 16384;
        if (ks < 7) {
            // issue next-tile stage into the other buffer (its readers finished
            // at the end-of-step barrier of iteration ks-1)
            char* nxt = smem + (((ks & 1) ^ 1)) * 16384;
            int kb = (ks + 1) * 64;
            gload_lds16(pAk + kb, nxt + sdst);
            gload_lds16(pAg + kb, nxt + 4096 + sdst);
            gload_lds16(pBk + kb, nxt + 8192 + sdst);
            gload_lds16(pBg + kb, nxt + 12288 + sdst);
            asm volatile("s_waitcnt vmcnt(4)" ::: "memory");   // cur's 4 loads done
        } else {
            asm volatile("s_waitcnt vmcnt(0)" ::: "memory");
        }
        __builtin_amdgcn_s_barrier();            // all waves: cur staged
        __builtin_amdgcn_sched_barrier(0);       // no LDS-read hoist above barrier

        short8 ak[2], bk[2];
#pragma unroll
        for (int m = 0; m < 2; ++m) ak[m] = *(const short8*)(cur + aoff[m]);
#pragma unroll
        for (int n = 0; n < 2; ++n) bk[n] = *(const short8*)(cur + 8192 + boff[n]);
        __builtin_amdgcn_s_setprio(1);
#pragma unroll
        for (int m = 0; m < 2; ++m)
#pragma unroll
            for (int n = 0; n < 2; ++n)
                acck[m][n] = __builtin_amdgcn_mfma_f32_16x16x32_bf16(ak[m], bk[n], acck[m][n], 0, 0, 0);
        __builtin_amdgcn_s_setprio(0);

        short8 ag[2], bg[2];
#pragma unroll
        for (int m = 0; m < 2; ++m) ag[m] = *(const short8*)(cur + 4096 + aoff[m]);
#pragma unroll
        for (int n = 0; n < 2; ++n) bg[n] = *(const short8*)(cur + 12288 + boff[n]);
        __builtin_amdgcn_s_setprio(1);
#pragma unroll
        for (int m = 0; m < 2; ++m)
#pragma unroll
            for (int n = 0; n < 2; ++n)
                accg[m][n] = __builtin_amdgcn_mfma_f32_16x16x32_bf16(ag[m], bg[n], accg[m][n], 0, 0, 0);
        __builtin_amdgcn_s_setprio(0);
        __builtin_amdgcn_sched_barrier(0);
        __builtin_amdgcn_s_barrier();            // all waves done reading cur
    }

    // --- epilogue: ratio + diag (in place) ---------------------------------
#pragma unroll
    for (int m = 0; m < 2; ++m)
#pragma unroll
        for (int j = 0; j < 4; ++j) {
            int lrow = wr * 32 + m * 16 + lg * 4 + j;
#pragma unroll
            for (int n = 0; n < 2; ++n) {
                float dk = acck[m][n][j];
                float dg = accg[m][n][j];
                float s = (dk + 1.0f + EPS_F) * __builtin_amdgcn_rcpf(dg + 1.0f + EPS_F);
                if (r0 + lrow == c0 + wc * 32 + n * 16 + lr) s = NEG_DIAG_F;
                acck[m][n][j] = s;
            }
        }

    // row maxes -> lmax[0..63]
#pragma unroll
    for (int m = 0; m < 2; ++m)
#pragma unroll
        for (int j = 0; j < 4; ++j) {
            float pm = fmaxf(acck[m][0][j], acck[m][1][j]);
#pragma unroll
            for (int off = 1; off < 16; off <<= 1)
                pm = fmaxf(pm, __shfl_xor(pm, off, 64));
            if (lr == 0) atomicMax(&lmax[wr * 32 + m * 16 + lg * 4 + j], __float_as_int(pm));
        }
    // col maxes -> lmax[64..127]
#pragma unroll
    for (int n = 0; n < 2; ++n) {
        float cm = acck[0][n][0];
#pragma unroll
        for (int m = 0; m < 2; ++m)
#pragma unroll
            for (int j = 0; j < 4; ++j) cm = fmaxf(cm, acck[m][n][j]);
        cm = fmaxf(cm, __shfl_xor(cm, 16, 64));
        cm = fmaxf(cm, __shfl_xor(cm, 32, 64));
        if (lg == 0) atomicMax(&lmax[64 + wc * 32 + n * 16 + lr], __float_as_int(cm));
    }

    // direct tile: bounce [row][col] then 256B-row coalesced stores
#pragma unroll
    for (int m = 0; m < 2; ++m)
#pragma unroll
        for (int n = 0; n < 2; ++n)
#pragma unroll
            for (int j = 0; j < 4; ++j)
                bnc[(wr * 32 + m * 16 + lg * 4 + j) * 66 + wc * 32 + n * 16 + lr] = acck[m][n][j];
    __syncthreads();   // bounce written + lmax atomics done

#pragma unroll
    for (int i = 0; i < 4; ++i) {
        int rr = i * 16 + (t >> 4);
        f32x4 v = *(const f32x4*)&bnc[rr * 66 + (t & 15) * 4];
        *(f32x4*)(out + (size_t)(r0 + rr) * N + c0 + (t & 15) * 4) = v;
    }
    if (t < 64) {
        P[(size_t)(r0 + t) * NPART + bx] = __int_as_float(lmax[t]);
    } else if (t < 128 && bx > by) {
        P[(size_t)(c0 + t - 64) * NPART + 64 + by] = __int_as_float(lmax[t]);
    }

    if (bx > by) {
        __syncthreads();   // direct-store reads done before overwrite
#pragma unroll
        for (int m = 0; m < 2; ++m)
#pragma unroll
            for (int n = 0; n < 2; ++n)
#pragma unroll
                for (int j = 0; j < 4; ++j)
                    bnc[(wc * 32 + n * 16 + lr) * 66 + wr * 32 + m * 16 + lg * 4 + j] = acck[m][n][j];
        __syncthreads();
#pragma unroll
        for (int i = 0; i < 4; ++i) {
            int rr = i * 16 + (t >> 4);
            f32x4 v = *(const f32x4*)&bnc[rr * 66 + (t & 15) * 4];
            *(f32x4*)(out + (size_t)(c0 + rr) * N + r0 + (t & 15) * 4) = v;
        }
    }
}

// ---------------------------------------------------------------------------
// Kernel 3: one block per row: m = max_j P[row][j]; out = exp(out - m).
// ---------------------------------------------------------------------------
__global__ void finalize_kernel(float* __restrict__ out, const float* __restrict__ P, int N) {
    int row = blockIdx.x;
    int t = threadIdx.x;            // 256
    int j = t & 63;
    float m = fmaxf(P[(size_t)row * NPART + j], P[(size_t)row * NPART + 64 + j]);
#pragma unroll
    for (int off = 1; off < 64; off <<= 1)
        m = fmaxf(m, __shfl_xor(m, off, 64));
    float4* o4 = (float4*)(out + (size_t)row * N);
    int n4 = N >> 2;
    for (int i = t; i < n4; i += 256) {
        float4 v = o4[i];
        v.x = __expf(v.x - m);
        v.y = __expf(v.y - m);
        v.z = __expf(v.z - m);
        v.w = __expf(v.w - m);
        o4[i] = v;
    }
}

// ---------------------------------------------------------------------------
extern "C" void kernel_launch(void* const* d_in, const int* in_sizes, int n_in,
                              void* d_out, int out_size, void* d_ws, size_t ws_size,
                              hipStream_t stream) {
    const float* fk = (const float*)d_in[1];
    const float* fg = (const float*)d_in[2];
    float* out = (float*)d_out;

    int N = (int)llround(sqrt((double)out_size));   // 4096
    int D = in_sizes[1] / N;                        // 256

    char* ws = (char*)d_ws;
    float* P = (float*)ws;                                          // N*128*4 = 2 MB
    __hip_bfloat16* fkb = (__hip_bfloat16*)(ws + (size_t)N * NPART * 4);
    __hip_bfloat16* fgb = (__hip_bfloat16*)(ws + (size_t)N * NPART * 4 + (size_t)N * D * 2);

    norm_cast_kernel<<<N, D, 0, stream>>>(fk, fg, fkb, fgb, P, N, D);

    gram64_kernel<<<dim3(N / 64, N / 64), 256, 0, stream>>>(fkb, fgb, out, P, N, D);

    finalize_kernel<<<N, 256, 0, stream>>>(out, P, N);
}